// Round 14
// baseline (568.269 us; speedup 1.0000x reference)
//
#include <hip/hip_runtime.h>
#include <math.h>

#define DEV __device__ __forceinline__

using f32x4  = __attribute__((ext_vector_type(4))) float;
using f32x16 = __attribute__((ext_vector_type(16))) float;
using bf8    = __attribute__((ext_vector_type(8))) short;
using bf4    = __attribute__((ext_vector_type(4))) short;

// B=16, CIN=256, N=1024, INNER=512, CTX_N=77, CTX_D=768, HEADS=8, DH=64.
// Seq-major [n][c] bf16 activations; every GEMM is C=A*B^T with K contiguous.
// Self-attention: R9 flash (XCD swizzle, LDS-staged K/V — best measured).
// mm v4: global_load_lds(16B) staging, BK=64, 8-chunk XOR swizzle,
// 32x32x16 MFMA inner loop (16 FLOP per LDS byte -> 2x the 16x16 LDS-bound
// ceiling; this is what capped mm and flash at ~20% MfmaUtil).

DEV short f2b(float x) {
  unsigned u = __builtin_bit_cast(unsigned, x);
  u += 0x7FFFu + ((u >> 16) & 1u);
  return (short)(u >> 16);
}
DEV float b2f(short s) {
  unsigned u = ((unsigned)(unsigned short)s) << 16;
  return __builtin_bit_cast(float, u);
}
DEV float ldin(const void* p, size_t i, int f) {
  return f ? reinterpret_cast<const float*>(p)[i]
           : b2f(reinterpret_cast<const short*>(p)[i]);
}

typedef const __attribute__((address_space(1))) void* gas_t;
typedef __attribute__((address_space(3))) void* las_t;
DEV void gl_lds16(const short* g, short* l) {
  __builtin_amdgcn_global_load_lds((gas_t)g, (las_t)l, 16, 0, 0);
}

DEV float wave_sum(float v) {
#pragma unroll
  for (int off = 32; off > 0; off >>= 1) v += __shfl_xor(v, off);
  return v;
}

// ---------------------------------------------------------------------------
__global__ __launch_bounds__(256) void probe_dtype(const unsigned short* __restrict__ x,
                                                   int* __restrict__ flag) {
  __shared__ int cnt;
  if (threadIdx.x == 0) cnt = 0;
  __syncthreads();
  int c = 0;
  for (int i = threadIdx.x; i < 8192; i += 256) {
    int e = (x[i] >> 7) & 0xFF;
    if (e == 0xFF || e == 0x00) ++c;
  }
  atomicAdd(&cnt, c);
  __syncthreads();
  if (threadIdx.x == 0) flag[0] = (cnt >= 4) ? 1 : 0;
}

// ---------------------------------------------------------------------------
__global__ __launch_bounds__(256) void gn_stats_ext(const void* __restrict__ x, size_t off,
                                                    const int* __restrict__ dflag,
                                                    float* __restrict__ stats,
                                                    int cpg, int C, int N, int G) {
  int f = dflag[0];
  int b = blockIdx.x / G;
  int g = blockIdx.x % G;
  size_t base = off + ((size_t)b * C + (size_t)g * cpg) * N;
  int count = cpg * N;
  float s = 0.f, ss = 0.f;
  if (f) {
    const float* p = (const float*)x + base;
    for (int i = threadIdx.x * 4; i < count; i += 1024) {
      float4 v = *(const float4*)&p[i];
      s += v.x + v.y + v.z + v.w;
      ss += v.x * v.x + v.y * v.y + v.z * v.z + v.w * v.w;
    }
  } else {
    const short* p = (const short*)x + base;
    for (int i = threadIdx.x * 8; i < count; i += 2048) {
      bf8 v = *(const bf8*)&p[i];
#pragma unroll
      for (int j = 0; j < 8; ++j) { float t = b2f(v[j]); s += t; ss += t * t; }
    }
  }
  s = wave_sum(s);
  ss = wave_sum(ss);
  __shared__ float r1[4], r2[4];
  int wid = threadIdx.x >> 6, lane = threadIdx.x & 63;
  if (lane == 0) { r1[wid] = s; r2[wid] = ss; }
  __syncthreads();
  if (threadIdx.x == 0) {
    s = r1[0] + r1[1] + r1[2] + r1[3];
    ss = r2[0] + r2[1] + r2[2] + r2[3];
    float mean = s / (float)count;
    float var = ss / (float)count - mean * mean;
    stats[blockIdx.x * 2 + 0] = mean;
    stats[blockIdx.x * 2 + 1] = rsqrtf(fmaxf(var, 0.f) + 1e-5f);
  }
}

__global__ __launch_bounds__(256) void gn_stats2(const short* __restrict__ h1,
                                                 float* __restrict__ stats) {
  int b = blockIdx.x >> 5, g = blockIdx.x & 31;
  int nr = threadIdx.x >> 1, half = (threadIdx.x & 1) * 8;
  float s = 0.f, ss = 0.f;
  for (int n = nr; n < 1024; n += 128) {
    bf8 v = *(const bf8*)&h1[((size_t)b * 1024 + n) * 512 + g * 16 + half];
#pragma unroll
    for (int j = 0; j < 8; ++j) { float t = b2f(v[j]); s += t; ss += t * t; }
  }
  s = wave_sum(s);
  ss = wave_sum(ss);
  __shared__ float r1[4], r2[4];
  int wid = threadIdx.x >> 6, lane = threadIdx.x & 63;
  if (lane == 0) { r1[wid] = s; r2[wid] = ss; }
  __syncthreads();
  if (threadIdx.x == 0) {
    s = r1[0] + r1[1] + r1[2] + r1[3];
    ss = r2[0] + r2[1] + r2[2] + r2[3];
    float mean = s / 16384.f;
    float var = ss / 16384.f - mean * mean;
    stats[blockIdx.x * 2 + 0] = mean;
    stats[blockIdx.x * 2 + 1] = rsqrtf(fmaxf(var, 0.f) + 1e-5f);
  }
}

__global__ __launch_bounds__(256) void make_affine(const float* __restrict__ stats,
                                                   const void* __restrict__ gamma,
                                                   const void* __restrict__ beta,
                                                   const int* __restrict__ dflag,
                                                   float* __restrict__ sA, float* __restrict__ tA,
                                                   int C, int cpg, int total) {
  int f = dflag[0];
  int i = blockIdx.x * blockDim.x + threadIdx.x;
  if (i >= total) return;
  int b = i / C, c = i % C;
  int G = C / cpg;
  int g = c / cpg;
  float mean = stats[(b * G + g) * 2 + 0];
  float rstd = stats[(b * G + g) * 2 + 1];
  float gm = ldin(gamma, c, f);
  float bt = ldin(beta, c, f);
  sA[i] = rstd * gm;
  tA[i] = bt - mean * rstd * gm;
}

// ---------------------------------------------------------------------------
__global__ __launch_bounds__(256) void transpose_affine(const void* __restrict__ x, size_t xoff,
                                                        const int* __restrict__ dflag,
                                                        const float* __restrict__ stats1,
                                                        const void* __restrict__ gamma,
                                                        const void* __restrict__ beta,
                                                        short* __restrict__ xT) {
  int f = dflag[0];
  __shared__ short xs[64 * 264];
  int b = blockIdx.y, n0 = blockIdx.x * 64;
  int tid = threadIdx.x;
  int cl = tid >> 3;
  int nl8 = (tid & 7) * 8;
#pragma unroll
  for (int p = 0; p < 8; ++p) {
    int c = p * 32 + cl;
    float mean = stats1[(b * 32 + (c >> 3)) * 2 + 0];
    float rstd = stats1[(b * 32 + (c >> 3)) * 2 + 1];
    float gm = ldin(gamma, c, f);
    float bt = ldin(beta, c, f);
    float sA = rstd * gm;
    float tA = bt - mean * sA;
    size_t gidx = xoff + ((size_t)b * 256 + c) * 1024 + n0 + nl8;
    float v[8];
    if (f) {
      const float* px = (const float*)x;
      float4 a = *(const float4*)&px[gidx];
      float4 bb = *(const float4*)&px[gidx + 4];
      v[0] = a.x; v[1] = a.y; v[2] = a.z; v[3] = a.w;
      v[4] = bb.x; v[5] = bb.y; v[6] = bb.z; v[7] = bb.w;
    } else {
      bf8 a = *(const bf8*)&((const short*)x)[gidx];
#pragma unroll
      for (int j = 0; j < 8; ++j) v[j] = b2f(a[j]);
    }
#pragma unroll
    for (int j = 0; j < 8; ++j) xs[(nl8 + j) * 264 + c] = f2b(v[j] * sA + tA);
  }
  __syncthreads();
  int nl = tid >> 2, cch = (tid & 3) * 64;
#pragma unroll
  for (int m = 0; m < 8; ++m)
    *(bf8*)&xT[((size_t)b * 1024 + n0 + nl) * 256 + cch + m * 8] =
        *(const bf8*)&xs[nl * 264 + cch + m * 8];
}

__global__ __launch_bounds__(256) void affine_apply(const short* __restrict__ h1,
                                                    const float* __restrict__ s2,
                                                    const float* __restrict__ t2,
                                                    short* __restrict__ out) {
  size_t gid = (size_t)blockIdx.x * 256 + threadIdx.x;
  size_t base = gid * 8;
  int bl = (int)(base >> 19);
  int c = (int)(base & 511);
  bf8 v = *(const bf8*)&h1[base];
  bf8 o;
#pragma unroll
  for (int j = 0; j < 8; ++j)
    o[j] = f2b(b2f(v[j]) * s2[bl * 512 + c + j] + t2[bl * 512 + c + j]);
  *(bf8*)&out[base] = o;
}

// ---------------------------------------------------------------------------
// Generic MFMA GEMM v4: OUT[z][p][q] = scale * sum_k Bm[p][k]*Am[q][k].
// BK=64, global_load_lds(16B) staging, 8-chunk XOR swizzle, 32x32x16 MFMA
// (per wave: 64x64 tile = 2x2 of 32x32; 16 MFMAs/iter, half the LDS frag
// bytes per FLOP of the 16x16x32 version). D layout (verified m74/m101):
// col = lane&31 -> p, row = (reg&3)+8*(reg>>2)+4*(lane>>5) -> q-local.
template <int A_EXT, int B_EXT, int OUT_T, int BIAS_P_, int BIAS_Q_, int RES_T>
__global__ __launch_bounds__(256) void mm(
    const void* __restrict__ Am, size_t aoff, int lda, size_t zsa,
    const void* __restrict__ Bm, size_t boff, int ldb, size_t zsb,
    void* __restrict__ Out, size_t ooff, int ldc, size_t zsc,
    const void* __restrict__ Res, size_t roff, size_t zsr, float res_scale,
    const void* __restrict__ biasP, const void* __restrict__ biasQ,
    const int* __restrict__ dflag, float scale, int P, int K) {
  const int f = dflag[0];
  __shared__ short lA[128 * 64];
  __shared__ short lB[128 * 64];
  const int tid = threadIdx.x;
  const int z = blockIdx.z;
  const int q0 = blockIdx.x * 128, p0 = blockIdx.y * 128;
  const int l = tid & 63;
  const int w = tid >> 6;
  const int wq = (w & 1) * 64, wp = (w >> 1) * 64;
  const int l31 = l & 31, lh = l >> 5;
  // DMA staging map: 8 rows/inst; lane l -> row l>>3, phys chunk l&7,
  // global chunk = (l&7) ^ ((l>>3)&7)
  const int drow = l >> 3;
  const int gchunk = (l & 7) ^ ((l >> 3) & 7);

  f32x16 acc[2][2];
#pragma unroll
  for (int i = 0; i < 2; ++i)
#pragma unroll
    for (int j = 0; j < 2; ++j)
#pragma unroll
      for (int r = 0; r < 16; ++r) acc[i][j][r] = 0.f;

  for (int kk = 0; kk < K; kk += 64) {
    __syncthreads();
    // ---- stage A tile (rows q0..q0+127, always valid) ----
    if (!(A_EXT && f)) {
      const short* As = (const short*)Am;
#pragma unroll
      for (int t = 0; t < 4; ++t) {
        int rl = w * 32 + t * 8;
        size_t g = aoff + (size_t)z * zsa + (size_t)(q0 + rl + drow) * lda + kk + gchunk * 8;
        gl_lds16(As + g, &lA[rl * 64]);
      }
    } else {
      const float* p = (const float*)Am;
      int r = tid >> 1;
      size_t g = aoff + (size_t)z * zsa + (size_t)(q0 + r) * lda + kk;
#pragma unroll
      for (int ci = 0; ci < 4; ++ci) {
        int pc = (tid & 1) * 4 + ci;
        int gc = pc ^ (r & 7);
        short tmp[8];
#pragma unroll
        for (int i2 = 0; i2 < 8; i2 += 4) {
          float4 t4 = *(const float4*)&p[g + gc * 8 + i2];
          tmp[i2] = f2b(t4.x); tmp[i2 + 1] = f2b(t4.y);
          tmp[i2 + 2] = f2b(t4.z); tmp[i2 + 3] = f2b(t4.w);
        }
        *(bf8*)&lA[r * 64 + pc * 8] = *(bf8*)&tmp[0];
      }
    }
    // ---- stage B tile (rows p0..p0+127, guard >= P) ----
    if (!(B_EXT && f)) {
      const short* Bs = (const short*)Bm;
#pragma unroll
      for (int t = 0; t < 4; ++t) {
        int rl = w * 32 + t * 8;
        int r = rl + drow;
        if (p0 + r < P) {
          size_t g = boff + (size_t)z * zsb + (size_t)(p0 + r) * ldb + kk + gchunk * 8;
          gl_lds16(Bs + g, &lB[rl * 64]);
        }
      }
    } else {
      const float* p = (const float*)Bm;
      int r = tid >> 1;
      bool valid = (p0 + r) < P;
      size_t g = boff + (size_t)z * zsb + (size_t)(p0 + r) * ldb + kk;
#pragma unroll
      for (int ci = 0; ci < 4; ++ci) {
        int pc = (tid & 1) * 4 + ci;
        int gc = pc ^ (r & 7);
        short tmp[8] = {0, 0, 0, 0, 0, 0, 0, 0};
        if (valid) {
#pragma unroll
          for (int i2 = 0; i2 < 8; i2 += 4) {
            float4 t4 = *(const float4*)&p[g + gc * 8 + i2];
            tmp[i2] = f2b(t4.x); tmp[i2 + 1] = f2b(t4.y);
            tmp[i2 + 2] = f2b(t4.z); tmp[i2 + 3] = f2b(t4.w);
          }
        }
        *(bf8*)&lB[r * 64 + pc * 8] = *(bf8*)&tmp[0];
      }
    }
    __syncthreads();  // drains vmcnt (DMA) + lgkmcnt before reads

#pragma unroll
    for (int ks = 0; ks < 4; ++ks) {
      int lc = lh + ks * 2;  // logical k-chunk (k = lc*8 .. +8)
      bf8 af2[2], bf2[2];
#pragma unroll
      for (int t = 0; t < 2; ++t) {
        int ra = wq + t * 32 + l31;
        af2[t] = *(const bf8*)&lA[ra * 64 + ((lc ^ (ra & 7)) * 8)];
        int rb = wp + t * 32 + l31;
        bf2[t] = *(const bf8*)&lB[rb * 64 + ((lc ^ (rb & 7)) * 8)];
      }
#pragma unroll
      for (int ti = 0; ti < 2; ++ti)
#pragma unroll
        for (int tj = 0; tj < 2; ++tj)
          acc[ti][tj] = __builtin_amdgcn_mfma_f32_32x32x16_bf16(af2[ti], bf2[tj], acc[ti][tj], 0, 0, 0);
    }
  }

  const size_t obase = ooff + (size_t)z * zsc;
#pragma unroll
  for (int tj = 0; tj < 2; ++tj) {
    int p = p0 + wp + tj * 32 + l31;
    if (p >= P) continue;
    float bp = BIAS_P_ ? ldin(biasP, p, f) : 0.f;
#pragma unroll
    for (int ti = 0; ti < 2; ++ti) {
#pragma unroll
      for (int g = 0; g < 4; ++g) {
        int q = q0 + wq + ti * 32 + g * 8 + lh * 4;
        float v[4];
#pragma unroll
        for (int r = 0; r < 4; ++r) {
          v[r] = acc[ti][tj][g * 4 + r] * scale + bp;
          if (BIAS_Q_) v[r] += ldin(biasQ, q + r, f);
        }
        if (RES_T == 1) {
          bf4 rv = *(const bf4*)&reinterpret_cast<const short*>(Res)[roff + (size_t)z * zsr + (size_t)p * ldc + q];
#pragma unroll
          for (int r = 0; r < 4; ++r) v[r] += res_scale * b2f(rv[r]);
        } else if (RES_T == 2) {
          size_t ri = roff + (size_t)z * zsr + (size_t)p * ldc + q;
          if (f) {
            float4 rf = *(const float4*)&reinterpret_cast<const float*>(Res)[ri];
            v[0] += res_scale * rf.x; v[1] += res_scale * rf.y;
            v[2] += res_scale * rf.z; v[3] += res_scale * rf.w;
          } else {
            bf4 rv = *(const bf4*)&reinterpret_cast<const short*>(Res)[ri];
#pragma unroll
            for (int r = 0; r < 4; ++r) v[r] += res_scale * b2f(rv[r]);
          }
        }
        size_t idx = obase + (size_t)p * ldc + q;
        if (OUT_T == 0) {
          bf4 o;
#pragma unroll
          for (int r = 0; r < 4; ++r) o[r] = f2b(v[r]);
          *(bf4*)&reinterpret_cast<short*>(Out)[idx] = o;
        } else if (OUT_T == 1) {
          f32x4 o = {v[0], v[1], v[2], v[3]};
          *(f32x4*)&reinterpret_cast<float*>(Out)[idx] = o;
        } else {
          if (f) {
            f32x4 o = {v[0], v[1], v[2], v[3]};
            *(f32x4*)&reinterpret_cast<float*>(Out)[idx] = o;
          } else {
            bf4 o;
#pragma unroll
            for (int r = 0; r < 4; ++r) o[r] = f2b(v[r]);
            *(bf4*)&reinterpret_cast<short*>(Out)[idx] = o;
          }
        }
      }
    }
  }
}

// ---------------------------------------------------------------------------
// Fused flash self-attention (R9 version verbatim — proven 121 us).
__global__ __launch_bounds__(256, 1) void flash_attn(const short* __restrict__ Q,
                                                     const short* __restrict__ Kb,
                                                     const short* __restrict__ VT,
                                                     short* __restrict__ O,
                                                     float scale, int NBm1) {
  __shared__ short KL[32 * 520];
  __shared__ short VL[256 * 40];
  __shared__ short PL[4 * 16 * 40];
  const int lin = blockIdx.x;
  const int b = lin & NBm1;
  const int rest = lin >> (31 - __builtin_clz(NBm1 + 1));
  const int dh = rest & 1;
  const int i0 = (rest >> 1) * 64;
  const int tid = threadIdx.x;
  const int w = tid >> 6, l = tid & 63, lm = l & 15, quad = l >> 4;

  const short* qb = Q + ((size_t)b * 1024 + i0 + w * 16 + lm) * 512;
  bf8 aq[16];
#pragma unroll
  for (int kc = 0; kc < 16; ++kc) aq[kc] = *(const bf8*)&qb[kc * 32 + quad * 8];

  f32x4 oacc[16];
#pragma unroll
  for (int df = 0; df < 16; ++df) oacc[df] = (f32x4){0.f, 0.f, 0.f, 0.f};
  float lsum[4] = {0.f, 0.f, 0.f, 0.f};

  const short* kbase = Kb + (size_t)b * 524288;
  const short* vbase = VT + (size_t)b * 524288 + (size_t)dh * 262144;

  const int krow = tid & 31, kc0 = (tid >> 5) * 64;

  for (int j0 = 0; j0 < 1024; j0 += 32) {
    __syncthreads();
    {
      const short* src = kbase + (size_t)(j0 + krow) * 512 + kc0;
      short* dst = &KL[krow * 520 + kc0];
#pragma unroll
      for (int i = 0; i < 8; ++i) *(bf8*)&dst[i * 8] = *(const bf8*)&src[i * 8];
    }
    {
      const short* src = vbase + (size_t)tid * 1024 + j0;
      short* dst = &VL[tid * 40];
#pragma unroll
      for (int i = 0; i < 4; ++i) *(bf8*)&dst[i * 8] = *(const bf8*)&src[i * 8];
    }
    __syncthreads();

    f32x4 sacc[2];
    sacc[0] = (f32x4){0.f, 0.f, 0.f, 0.f};
    sacc[1] = (f32x4){0.f, 0.f, 0.f, 0.f};
#pragma unroll
    for (int kc = 0; kc < 16; ++kc) {
#pragma unroll
      for (int jf = 0; jf < 2; ++jf) {
        bf8 bk = *(const bf8*)&KL[(jf * 16 + lm) * 520 + kc * 32 + quad * 8];
        sacc[jf] = __builtin_amdgcn_mfma_f32_16x16x32_bf16(aq[kc], bk, sacc[jf], 0, 0, 0);
      }
    }
#pragma unroll
    for (int jf = 0; jf < 2; ++jf)
#pragma unroll
      for (int r = 0; r < 4; ++r) sacc[jf][r] = __expf(sacc[jf][r] * scale);
#pragma unroll
    for (int r = 0; r < 4; ++r) {
      float ts = sacc[0][r] + sacc[1][r];
      ts += __shfl_xor(ts, 1);
      ts += __shfl_xor(ts, 2);
      ts += __shfl_xor(ts, 4);
      ts += __shfl_xor(ts, 8);
      lsum[r] += ts;
      int row = quad * 4 + r;
      PL[w * 640 + row * 40 + lm] = f2b(sacc[0][r]);
      PL[w * 640 + row * 40 + 16 + lm] = f2b(sacc[1][r]);
    }
    bf8 ap = *(const bf8*)&PL[w * 640 + lm * 40 + quad * 8];
#pragma unroll
    for (int df = 0; df < 16; ++df) {
      bf8 bv = *(const bf8*)&VL[(df * 16 + lm) * 40 + quad * 8];
      oacc[df] = __builtin_amdgcn_mfma_f32_16x16x32_bf16(ap, bv, oacc[df], 0, 0, 0);
    }
  }
  float inv[4];
#pragma unroll
  for (int r = 0; r < 4; ++r) inv[r] = 1.f / lsum[r];
  short* ob = O + ((size_t)b * 1024 + i0 + w * 16 + quad * 4) * 512 + dh * 256;
#pragma unroll
  for (int df = 0; df < 16; ++df)
#pragma unroll
    for (int r = 0; r < 4; ++r)
      ob[(size_t)r * 512 + df * 16 + lm] = f2b(oacc[df][r] * inv[r]);
}

// ---------------------------------------------------------------------------
// Fused cross-attention via MFMA (unchanged).
__global__ __launch_bounds__(256) void cross_attn_mfma(const short* __restrict__ q2,
                                                       const short* __restrict__ k2,
                                                       const short* __restrict__ v2,
                                                       short* __restrict__ o2) {
  __shared__ short Pl[64 * 104];
  __shared__ short VTl[64 * 104];
  const int b = blockIdx.z, h = blockIdx.y, i0 = blockIdx.x * 64;
  const int tid = threadIdx.x;
  const int w = tid >> 6, l = tid & 63, lm = l & 15, quad = l >> 4;

  for (int idx = tid; idx < 64 * 104 / 4; idx += 256)
    *(bf4*)&VTl[idx * 4] = (bf4){0, 0, 0, 0};
  __syncthreads();
  for (int idx = tid; idx < 77 * 64; idx += 256) {
    int j = idx >> 6, d = idx & 63;
    VTl[d * 104 + j] = v2[(size_t)b * 39424 + j * 512 + h * 64 + d];
  }

  const short* qb = q2 + ((size_t)b * 1024 + i0 + w * 16 + lm) * 512 + h * 64;
  bf8 aq0 = *(const bf8*)&qb[quad * 8];
  bf8 aq1 = *(const bf8*)&qb[32 + quad * 8];
  const short* kb = k2 + (size_t)b * 39424 + h * 64;
  f32x4 sacc[5];
#pragma unroll
  for (int jt = 0; jt < 5; ++jt) sacc[jt] = (f32x4){0.f, 0.f, 0.f, 0.f};
#pragma unroll
  for (int jt = 0; jt < 5; ++jt) {
    int j = jt * 16 + lm;
    bf8 b0 = {0, 0, 0, 0, 0, 0, 0, 0}, b1 = {0, 0, 0, 0, 0, 0, 0, 0};
    if (j < 77) {
      b0 = *(const bf8*)&kb[j * 512 + quad * 8];
      b1 = *(const bf8*)&kb[j * 512 + 32 + quad * 8];
    }
    sacc[jt] = __builtin_amdgcn_mfma_f32_16x16x32_bf16(aq0, b0, sacc[jt], 0, 0, 0);
    sacc[jt] = __builtin_amdgcn_mfma_f32_16x16x32_bf16(aq1, b1, sacc[jt], 0, 0, 0);
  }
#pragma unroll
  for (int jt = 0; jt < 5; ++jt) {
    bool valid = (jt * 16 + lm) < 77;
#pragma unroll
    for (int r = 0; r < 4; ++r)
      sacc[jt][r] = valid ? sacc[jt][r] * 0.125f : -1e30f;
  }
#pragma unroll
  for (int r = 0; r < 4; ++r) {
    float mx = sacc[0][r];
#pragma unroll
    for (int jt = 1; jt < 5; ++jt) mx = fmaxf(mx, sacc[jt][r]);
    mx = fmaxf(mx, __shfl_xor(mx, 1));
    mx = fmaxf(mx, __shfl_xor(mx, 2));
    mx = fmaxf(mx, __shfl_xor(mx, 4));
    mx = fmaxf(mx, __shfl_xor(mx, 8));
    float s = 0.f;
    float e[5];
#pragma unroll
    for (int jt = 0; jt < 5; ++jt) { e[jt] = __expf(sacc[jt][r] - mx); s += e[jt]; }
    s += __shfl_xor(s, 1);
    s += __shfl_xor(s, 2);
    s += __shfl_xor(s, 4);
    s += __shfl_xor(s, 8);
    float iv = 1.f / s;
    int row = w * 16 + quad * 4 + r;
#pragma unroll
    for (int jt = 0; jt < 5; ++jt) Pl[row * 104 + jt * 16 + lm] = f2b(e[jt] * iv);
  }
#pragma unroll
  for (int r = 0; r < 4; ++r) Pl[(w * 16 + quad * 4 + r) * 104 + 80 + lm] = 0;
  __syncthreads();

  f32x4 oacc[4];
#pragma unroll
  for (int dt = 0; dt < 4; ++dt) oacc[dt] = (f32x4){0.f, 0.f, 0.f, 0.f};
#pragma unroll
  for (int kc = 0; kc < 3; ++kc) {
    bf8 ap = *(const bf8*)&Pl[(w * 16 + lm) * 104 + kc * 32 + quad * 8];
#pragma unroll
    for (int dt = 0; dt < 4; ++dt) {
      bf8 bv = *(const bf8*)&VTl[(dt * 16 + lm) * 104 + kc * 32 + quad * 8];
      oacc[dt] = __builtin_amdgcn_mfma_f32_16x16x32_bf16(ap, bv, oacc[dt], 0, 0, 0);
    }
  }
  short* ob = o2 + ((size_t)b * 1024 + i0 + w * 16 + quad * 4) * 512 + h * 64;
#pragma unroll
  for (int dt = 0; dt < 4; ++dt)
#pragma unroll
    for (int r = 0; r < 4; ++r)
      ob[(size_t)r * 512 + dt * 16 + lm] = f2b(oacc[dt][r]);
}

// ---------------------------------------------------------------------------
extern "C" void kernel_launch(void* const* d_in, const int* in_sizes, int n_in,
                              void* d_out, int out_size, void* d_ws, size_t ws_size,
                              hipStream_t stream) {
  const void* x       = d_in[0];
  const void* ctx     = d_in[1];
  const void* gn1_g   = d_in[2];
  const void* gn1_b   = d_in[3];
  const void* w_in    = d_in[4];
  const void* b_in    = d_in[5];
  const void* sa_wk   = d_in[6];
  const void* sa_wq   = d_in[7];
  const void* sa_wv   = d_in[8];
  const void* sa_wp   = d_in[9];
  const void* sa_gn_g = d_in[10];
  const void* sa_gn_b = d_in[11];
  const void* ca_wq   = d_in[12];
  const void* ca_wk   = d_in[13];
  const void* ca_wv   = d_in[14];
  const void* ca_wo   = d_in[15];
  const void* ca_bo   = d_in[16];
  const void* w_out   = d_in[17];
  const void* b_out   = d_in[18];

  const int B = 16;
  int NB = 16;
  while (NB > 1 && 131072ull + (size_t)NB * 5767168ull > ws_size) NB >>= 1;

  char* base = reinterpret_cast<char*>(d_ws);
  int* flagp = reinterpret_cast<int*>(base);
  float* smf = reinterpret_cast<float*>(base + 1024);
  float* stats1 = smf;
  float* stats2 = smf + 1024;
  float* s2 = smf + 10240;
  float* t2 = smf + 18432;
  char* big = base + 131072;
  const size_t MB = 1048576;
  short* U0 = (short*)(big + 0 * (size_t)NB * MB);
  short* U1 = (short*)(big + 1 * (size_t)NB * MB);
  short* U2 = (short*)(big + 2 * (size_t)NB * MB);
  short* U3 = (short*)(big + 3 * (size_t)NB * MB);
  short* U4 = (short*)(big + 4 * (size_t)NB * MB);
  char* Sreg = big + 5 * (size_t)NB * MB;
  short* xT = (short*)Sreg;
  short* k2 = (short*)Sreg;
  short* v2 = (short*)(Sreg + (size_t)NB * 78848);

  probe_dtype<<<1, 256, 0, stream>>>((const unsigned short*)x, flagp);

  const float qk_scale = 0.044194173824159216f;

  for (int b0 = 0; b0 < B; b0 += NB) {
    size_t xoff = (size_t)b0 * 262144;
    size_t coff = (size_t)b0 * 59136;

    gn_stats_ext<<<NB * 32, 256, 0, stream>>>(x, xoff, flagp, stats1, 8, 256, 1024, 32);
    transpose_affine<<<dim3(16, NB), 256, 0, stream>>>(x, xoff, flagp, stats1, gn1_g, gn1_b, xT);
    mm<1, 0, 0, 0, 1, 0><<<dim3(4, 8, NB), 256, 0, stream>>>(
        w_in, 0, 256, 0, xT, 0, 256, 262144, U0, 0, 512, 524288,
        nullptr, 0, 0, 0.f, nullptr, b_in, flagp, 1.f, 1024, 256);

    gn_stats2<<<NB * 32, 256, 0, stream>>>(U0, stats2);
    make_affine<<<(NB * 512 + 255) / 256, 256, 0, stream>>>(stats2, sa_gn_g, sa_gn_b, flagp, s2, t2, 512, 16, NB * 512);
    affine_apply<<<NB * 256, 256, 0, stream>>>(U0, s2, t2, U1);

    mm<1, 0, 0, 0, 0, 0><<<dim3(4, 8, NB), 256, 0, stream>>>(
        sa_wq, 0, 512, 0, U1, 0, 512, 524288, U2, 0, 512, 524288,
        nullptr, 0, 0, 0.f, nullptr, nullptr, flagp, 1.f, 1024, 512);
    mm<1, 0, 0, 0, 0, 0><<<dim3(4, 8, NB), 256, 0, stream>>>(
        sa_wk, 0, 512, 0, U1, 0, 512, 524288, U3, 0, 512, 524288,
        nullptr, 0, 0, 0.f, nullptr, nullptr, flagp, 1.f, 1024, 512);
    mm<0, 1, 0, 0, 0, 0><<<dim3(8, 4, NB), 256, 0, stream>>>(
        U1, 0, 512, 524288, sa_wv, 0, 512, 0, U4, 0, 1024, 524288,
        nullptr, 0, 0, 0.f, nullptr, nullptr, flagp, 1.f, 512, 512);

    flash_attn<<<dim3(32 * NB), 256, 0, stream>>>(U2, U3, U4, U1, qk_scale, NB - 1);

    mm<1, 0, 0, 0, 0, 1><<<dim3(4, 8, NB), 256, 0, stream>>>(
        sa_wp, 0, 512, 0, U1, 0, 512, 524288, U3, 0, 512, 524288,
        U0, 0, 524288, 2.f, nullptr, nullptr, flagp, 1.f, 1024, 512);

    mm<1, 0, 0, 0, 0, 0><<<dim3(4, 8, NB), 256, 0, stream>>>(
        ca_wq, 0, 512, 0, U3, 0, 512, 524288, U2, 0, 512, 524288,
        nullptr, 0, 0, 0.f, nullptr, nullptr, flagp, 1.f, 1024, 512);
    mm<1, 1, 0, 0, 0, 0><<<dim3(4, 1, NB), 256, 0, stream>>>(
        ca_wk, 0, 768, 0, ctx, coff, 768, 59136, k2, 0, 512, 39424,
        nullptr, 0, 0, 0.f, nullptr, nullptr, flagp, 1.f, 77, 768);
    mm<1, 1, 0, 0, 0, 0><<<dim3(4, 1, NB), 256, 0, stream>>>(
        ca_wv, 0, 768, 0, ctx, coff, 768, 59136, v2, 0, 512, 39424,
        nullptr, 0, 0, 0.f, nullptr, nullptr, flagp, 1.f, 77, 768);
    cross_attn_mfma<<<dim3(16, 8, NB), 256, 0, stream>>>(U2, k2, v2, U4);

    mm<1, 0, 0, 0, 1, 1><<<dim3(4, 8, NB), 256, 0, stream>>>(
        ca_wo, 0, 512, 0, U4, 0, 512, 524288, U0, 0, 512, 524288,
        U3, 0, 524288, 1.f, nullptr, ca_bo, flagp, 1.f, 1024, 512);

    mm<0, 1, 2, 1, 0, 2><<<dim3(8, 2, NB), 256, 0, stream>>>(
        U0, 0, 512, 524288, w_out, 0, 512, 0, d_out, xoff, 1024, 262144,
        x, xoff, 262144, 1.f, b_out, nullptr, flagp, 1.f, 256, 512);
  }

  (void)in_sizes; (void)n_in; (void)out_size;
}

// Round 15
// 523.232 us; speedup vs baseline: 1.0861x; 1.0861x over previous
//
#include <hip/hip_runtime.h>
#include <math.h>

#define DEV __device__ __forceinline__

using f32x4 = __attribute__((ext_vector_type(4))) float;
using bf8   = __attribute__((ext_vector_type(8))) short;
using bf4   = __attribute__((ext_vector_type(4))) short;

// B=16, CIN=256, N=1024, INNER=512, CTX_N=77, CTX_D=768, HEADS=8, DH=64.
// Seq-major [n][c] bf16 activations; every GEMM is C=A*B^T with K contiguous.
// Self-attention: R9 flash (XCD swizzle, LDS-staged K/V — best measured).
// mm: R13's proven version (16x16x32, BK=64, global_load_lds(16B), XOR
// swizzle) + dual-weight merge (independent GEMM pairs in one launch).

DEV short f2b(float x) {
  unsigned u = __builtin_bit_cast(unsigned, x);
  u += 0x7FFFu + ((u >> 16) & 1u);
  return (short)(u >> 16);
}
DEV float b2f(short s) {
  unsigned u = ((unsigned)(unsigned short)s) << 16;
  return __builtin_bit_cast(float, u);
}
DEV float ldin(const void* p, size_t i, int f) {
  return f ? reinterpret_cast<const float*>(p)[i]
           : b2f(reinterpret_cast<const short*>(p)[i]);
}

typedef const __attribute__((address_space(1))) void* gas_t;
typedef __attribute__((address_space(3))) void* las_t;
DEV void gl_lds16(const short* g, short* l) {
  __builtin_amdgcn_global_load_lds((gas_t)g, (las_t)l, 16, 0, 0);
}

DEV float wave_sum(float v) {
#pragma unroll
  for (int off = 32; off > 0; off >>= 1) v += __shfl_xor(v, off);
  return v;
}

// ---------------------------------------------------------------------------
__global__ __launch_bounds__(256) void probe_dtype(const unsigned short* __restrict__ x,
                                                   int* __restrict__ flag) {
  __shared__ int cnt;
  if (threadIdx.x == 0) cnt = 0;
  __syncthreads();
  int c = 0;
  for (int i = threadIdx.x; i < 8192; i += 256) {
    int e = (x[i] >> 7) & 0xFF;
    if (e == 0xFF || e == 0x00) ++c;
  }
  atomicAdd(&cnt, c);
  __syncthreads();
  if (threadIdx.x == 0) flag[0] = (cnt >= 4) ? 1 : 0;
}

// ---------------------------------------------------------------------------
__global__ __launch_bounds__(256) void gn_stats_ext(const void* __restrict__ x, size_t off,
                                                    const int* __restrict__ dflag,
                                                    float* __restrict__ stats,
                                                    int cpg, int C, int N, int G) {
  int f = dflag[0];
  int b = blockIdx.x / G;
  int g = blockIdx.x % G;
  size_t base = off + ((size_t)b * C + (size_t)g * cpg) * N;
  int count = cpg * N;
  float s = 0.f, ss = 0.f;
  if (f) {
    const float* p = (const float*)x + base;
    for (int i = threadIdx.x * 4; i < count; i += 1024) {
      float4 v = *(const float4*)&p[i];
      s += v.x + v.y + v.z + v.w;
      ss += v.x * v.x + v.y * v.y + v.z * v.z + v.w * v.w;
    }
  } else {
    const short* p = (const short*)x + base;
    for (int i = threadIdx.x * 8; i < count; i += 2048) {
      bf8 v = *(const bf8*)&p[i];
#pragma unroll
      for (int j = 0; j < 8; ++j) { float t = b2f(v[j]); s += t; ss += t * t; }
    }
  }
  s = wave_sum(s);
  ss = wave_sum(ss);
  __shared__ float r1[4], r2[4];
  int wid = threadIdx.x >> 6, lane = threadIdx.x & 63;
  if (lane == 0) { r1[wid] = s; r2[wid] = ss; }
  __syncthreads();
  if (threadIdx.x == 0) {
    s = r1[0] + r1[1] + r1[2] + r1[3];
    ss = r2[0] + r2[1] + r2[2] + r2[3];
    float mean = s / (float)count;
    float var = ss / (float)count - mean * mean;
    stats[blockIdx.x * 2 + 0] = mean;
    stats[blockIdx.x * 2 + 1] = rsqrtf(fmaxf(var, 0.f) + 1e-5f);
  }
}

__global__ __launch_bounds__(256) void gn_stats2(const short* __restrict__ h1,
                                                 float* __restrict__ stats) {
  int b = blockIdx.x >> 5, g = blockIdx.x & 31;
  int nr = threadIdx.x >> 1, half = (threadIdx.x & 1) * 8;
  float s = 0.f, ss = 0.f;
  for (int n = nr; n < 1024; n += 128) {
    bf8 v = *(const bf8*)&h1[((size_t)b * 1024 + n) * 512 + g * 16 + half];
#pragma unroll
    for (int j = 0; j < 8; ++j) { float t = b2f(v[j]); s += t; ss += t * t; }
  }
  s = wave_sum(s);
  ss = wave_sum(ss);
  __shared__ float r1[4], r2[4];
  int wid = threadIdx.x >> 6, lane = threadIdx.x & 63;
  if (lane == 0) { r1[wid] = s; r2[wid] = ss; }
  __syncthreads();
  if (threadIdx.x == 0) {
    s = r1[0] + r1[1] + r1[2] + r1[3];
    ss = r2[0] + r2[1] + r2[2] + r2[3];
    float mean = s / 16384.f;
    float var = ss / 16384.f - mean * mean;
    stats[blockIdx.x * 2 + 0] = mean;
    stats[blockIdx.x * 2 + 1] = rsqrtf(fmaxf(var, 0.f) + 1e-5f);
  }
}

__global__ __launch_bounds__(256) void make_affine(const float* __restrict__ stats,
                                                   const void* __restrict__ gamma,
                                                   const void* __restrict__ beta,
                                                   const int* __restrict__ dflag,
                                                   float* __restrict__ sA, float* __restrict__ tA,
                                                   int C, int cpg, int total) {
  int f = dflag[0];
  int i = blockIdx.x * blockDim.x + threadIdx.x;
  if (i >= total) return;
  int b = i / C, c = i % C;
  int G = C / cpg;
  int g = c / cpg;
  float mean = stats[(b * G + g) * 2 + 0];
  float rstd = stats[(b * G + g) * 2 + 1];
  float gm = ldin(gamma, c, f);
  float bt = ldin(beta, c, f);
  sA[i] = rstd * gm;
  tA[i] = bt - mean * rstd * gm;
}

// ---------------------------------------------------------------------------
__global__ __launch_bounds__(256) void transpose_affine(const void* __restrict__ x, size_t xoff,
                                                        const int* __restrict__ dflag,
                                                        const float* __restrict__ stats1,
                                                        const void* __restrict__ gamma,
                                                        const void* __restrict__ beta,
                                                        short* __restrict__ xT) {
  int f = dflag[0];
  __shared__ short xs[64 * 264];
  int b = blockIdx.y, n0 = blockIdx.x * 64;
  int tid = threadIdx.x;
  int cl = tid >> 3;
  int nl8 = (tid & 7) * 8;
#pragma unroll
  for (int p = 0; p < 8; ++p) {
    int c = p * 32 + cl;
    float mean = stats1[(b * 32 + (c >> 3)) * 2 + 0];
    float rstd = stats1[(b * 32 + (c >> 3)) * 2 + 1];
    float gm = ldin(gamma, c, f);
    float bt = ldin(beta, c, f);
    float sA = rstd * gm;
    float tA = bt - mean * sA;
    size_t gidx = xoff + ((size_t)b * 256 + c) * 1024 + n0 + nl8;
    float v[8];
    if (f) {
      const float* px = (const float*)x;
      float4 a = *(const float4*)&px[gidx];
      float4 bb = *(const float4*)&px[gidx + 4];
      v[0] = a.x; v[1] = a.y; v[2] = a.z; v[3] = a.w;
      v[4] = bb.x; v[5] = bb.y; v[6] = bb.z; v[7] = bb.w;
    } else {
      bf8 a = *(const bf8*)&((const short*)x)[gidx];
#pragma unroll
      for (int j = 0; j < 8; ++j) v[j] = b2f(a[j]);
    }
#pragma unroll
    for (int j = 0; j < 8; ++j) xs[(nl8 + j) * 264 + c] = f2b(v[j] * sA + tA);
  }
  __syncthreads();
  int nl = tid >> 2, cch = (tid & 3) * 64;
#pragma unroll
  for (int m = 0; m < 8; ++m)
    *(bf8*)&xT[((size_t)b * 1024 + n0 + nl) * 256 + cch + m * 8] =
        *(const bf8*)&xs[nl * 264 + cch + m * 8];
}

__global__ __launch_bounds__(256) void affine_apply(const short* __restrict__ h1,
                                                    const float* __restrict__ s2,
                                                    const float* __restrict__ t2,
                                                    short* __restrict__ out) {
  size_t gid = (size_t)blockIdx.x * 256 + threadIdx.x;
  size_t base = gid * 8;
  int bl = (int)(base >> 19);
  int c = (int)(base & 511);
  bf8 v = *(const bf8*)&h1[base];
  bf8 o;
#pragma unroll
  for (int j = 0; j < 8; ++j)
    o[j] = f2b(b2f(v[j]) * s2[bl * 512 + c + j] + t2[bl * 512 + c + j]);
  *(bf8*)&out[base] = o;
}

// ---------------------------------------------------------------------------
// Generic MFMA GEMM (R13 version, proven): OUT[z][p][q] = scale *
// sum_k Bm[p][k]*Am[q][k]. BK=64, global_load_lds(16B) staging, 8-chunk XOR
// swizzle, 16x16x32 MFMA. Dual-weight merge: if blockIdx.y >= ysplit, use
// Am2/Out2 with p-tile index (blockIdx.y - ysplit) — merges independent
// GEMM pairs that share the B operand into one launch (kills a stream tail).
template <int A_EXT, int B_EXT, int OUT_T, int BIAS_P_, int BIAS_Q_, int RES_T>
__global__ __launch_bounds__(256) void mm(
    const void* __restrict__ Am, size_t aoff, int lda, size_t zsa,
    const void* __restrict__ Bm, size_t boff, int ldb, size_t zsb,
    void* __restrict__ Out, size_t ooff, int ldc, size_t zsc,
    const void* __restrict__ Res, size_t roff, size_t zsr, float res_scale,
    const void* __restrict__ biasP, const void* __restrict__ biasQ,
    const int* __restrict__ dflag, float scale, int P, int K,
    const void* __restrict__ Am2, void* __restrict__ Out2, int ysplit) {
  const int f = dflag[0];
  __shared__ short lA[128 * 64];
  __shared__ short lB[128 * 64];
  const int tid = threadIdx.x;
  const int z = blockIdx.z;
  int yy = blockIdx.y;
  const void* Ause = Am;
  void* Ouse = Out;
  if (yy >= ysplit) { Ause = Am2; Ouse = Out2; yy -= ysplit; }
  const int q0 = blockIdx.x * 128, p0 = yy * 128;
  const int l = tid & 63;
  const int w = tid >> 6;
  const int wq = (w & 1) * 64, wp = (w >> 1) * 64;
  const int lm = l & 15, quad = l >> 4;
  const int drow = l >> 3;
  const int gchunk = (l & 7) ^ ((l >> 3) & 7);
  const int rx = lm & 7;

  f32x4 acc[4][4];
#pragma unroll
  for (int i = 0; i < 4; ++i)
#pragma unroll
    for (int j = 0; j < 4; ++j) acc[i][j] = (f32x4){0.f, 0.f, 0.f, 0.f};

  for (int kk = 0; kk < K; kk += 64) {
    __syncthreads();
    // ---- stage A tile (rows q0..q0+127, always valid; A = Ause) ----
    if (!(A_EXT && f)) {
      const short* As = (const short*)Ause;
#pragma unroll
      for (int t = 0; t < 4; ++t) {
        int rl = w * 32 + t * 8;
        size_t g = aoff + (size_t)z * zsa + (size_t)(q0 + rl + drow) * lda + kk + gchunk * 8;
        gl_lds16(As + g, &lA[rl * 64]);
      }
    } else {
      const float* p = (const float*)Ause;
      int r = tid >> 1;
      size_t g = aoff + (size_t)z * zsa + (size_t)(q0 + r) * lda + kk;
#pragma unroll
      for (int ci = 0; ci < 4; ++ci) {
        int pc = (tid & 1) * 4 + ci;
        int gc = pc ^ (r & 7);
        short tmp[8];
#pragma unroll
        for (int i2 = 0; i2 < 8; i2 += 4) {
          float4 t4 = *(const float4*)&p[g + gc * 8 + i2];
          tmp[i2] = f2b(t4.x); tmp[i2 + 1] = f2b(t4.y);
          tmp[i2 + 2] = f2b(t4.z); tmp[i2 + 3] = f2b(t4.w);
        }
        *(bf8*)&lA[r * 64 + pc * 8] = *(bf8*)&tmp[0];
      }
    }
    // ---- stage B tile (rows p0..p0+127, guard >= P) ----
    if (!(B_EXT && f)) {
      const short* Bs = (const short*)Bm;
#pragma unroll
      for (int t = 0; t < 4; ++t) {
        int rl = w * 32 + t * 8;
        int r = rl + drow;
        if (p0 + r < P) {
          size_t g = boff + (size_t)z * zsb + (size_t)(p0 + r) * ldb + kk + gchunk * 8;
          gl_lds16(Bs + g, &lB[rl * 64]);
        }
      }
    } else {
      const float* p = (const float*)Bm;
      int r = tid >> 1;
      bool valid = (p0 + r) < P;
      size_t g = boff + (size_t)z * zsb + (size_t)(p0 + r) * ldb + kk;
#pragma unroll
      for (int ci = 0; ci < 4; ++ci) {
        int pc = (tid & 1) * 4 + ci;
        int gc = pc ^ (r & 7);
        short tmp[8] = {0, 0, 0, 0, 0, 0, 0, 0};
        if (valid) {
#pragma unroll
          for (int i2 = 0; i2 < 8; i2 += 4) {
            float4 t4 = *(const float4*)&p[g + gc * 8 + i2];
            tmp[i2] = f2b(t4.x); tmp[i2 + 1] = f2b(t4.y);
            tmp[i2 + 2] = f2b(t4.z); tmp[i2 + 3] = f2b(t4.w);
          }
        }
        *(bf8*)&lB[r * 64 + pc * 8] = *(bf8*)&tmp[0];
      }
    }
    __syncthreads();  // drains vmcnt (DMA) + lgkmcnt before reads

#pragma unroll
    for (int s = 0; s < 2; ++s) {
      bf8 af[4], bfr[4];
#pragma unroll
      for (int i = 0; i < 4; ++i)
        af[i] = *(const bf8*)&lA[(wq + i * 16 + lm) * 64 + (((s * 4 + quad) ^ rx) * 8)];
#pragma unroll
      for (int i = 0; i < 4; ++i)
        bfr[i] = *(const bf8*)&lB[(wp + i * 16 + lm) * 64 + (((s * 4 + quad) ^ rx) * 8)];
#pragma unroll
      for (int qi = 0; qi < 4; ++qi)
#pragma unroll
        for (int pi = 0; pi < 4; ++pi)
          acc[qi][pi] = __builtin_amdgcn_mfma_f32_16x16x32_bf16(af[qi], bfr[pi], acc[qi][pi], 0, 0, 0);
    }
  }

  const size_t obase = ooff + (size_t)z * zsc;
#pragma unroll
  for (int pi = 0; pi < 4; ++pi) {
    int p = p0 + wp + pi * 16 + lm;
    if (p >= P) continue;
    float bp = BIAS_P_ ? ldin(biasP, p, f) : 0.f;
#pragma unroll
    for (int qi = 0; qi < 4; ++qi) {
      int q = q0 + wq + qi * 16 + quad * 4;
      f32x4 d = acc[qi][pi];
      float v[4];
#pragma unroll
      for (int r = 0; r < 4; ++r) {
        v[r] = d[r] * scale + bp;
        if (BIAS_Q_) v[r] += ldin(biasQ, q + r, f);
      }
      if (RES_T == 1) {
        bf4 rv = *(const bf4*)&reinterpret_cast<const short*>(Res)[roff + (size_t)z * zsr + (size_t)p * ldc + q];
#pragma unroll
        for (int r = 0; r < 4; ++r) v[r] += res_scale * b2f(rv[r]);
      } else if (RES_T == 2) {
        size_t ri = roff + (size_t)z * zsr + (size_t)p * ldc + q;
        if (f) {
          float4 rf = *(const float4*)&reinterpret_cast<const float*>(Res)[ri];
          v[0] += res_scale * rf.x; v[1] += res_scale * rf.y;
          v[2] += res_scale * rf.z; v[3] += res_scale * rf.w;
        } else {
          bf4 rv = *(const bf4*)&reinterpret_cast<const short*>(Res)[ri];
#pragma unroll
          for (int r = 0; r < 4; ++r) v[r] += res_scale * b2f(rv[r]);
        }
      }
      size_t idx = obase + (size_t)p * ldc + q;
      if (OUT_T == 0) {
        bf4 o;
#pragma unroll
        for (int r = 0; r < 4; ++r) o[r] = f2b(v[r]);
        *(bf4*)&reinterpret_cast<short*>(Ouse)[idx] = o;
      } else if (OUT_T == 1) {
        f32x4 o = {v[0], v[1], v[2], v[3]};
        *(f32x4*)&reinterpret_cast<float*>(Ouse)[idx] = o;
      } else {
        if (f) {
          f32x4 o = {v[0], v[1], v[2], v[3]};
          *(f32x4*)&reinterpret_cast<float*>(Ouse)[idx] = o;
        } else {
          bf4 o;
#pragma unroll
          for (int r = 0; r < 4; ++r) o[r] = f2b(v[r]);
          *(bf4*)&reinterpret_cast<short*>(Ouse)[idx] = o;
        }
      }
    }
  }
}

// ---------------------------------------------------------------------------
// Fused flash self-attention (R9 version verbatim — proven 121 us).
__global__ __launch_bounds__(256, 1) void flash_attn(const short* __restrict__ Q,
                                                     const short* __restrict__ Kb,
                                                     const short* __restrict__ VT,
                                                     short* __restrict__ O,
                                                     float scale, int NBm1) {
  __shared__ short KL[32 * 520];
  __shared__ short VL[256 * 40];
  __shared__ short PL[4 * 16 * 40];
  const int lin = blockIdx.x;
  const int b = lin & NBm1;
  const int rest = lin >> (31 - __builtin_clz(NBm1 + 1));
  const int dh = rest & 1;
  const int i0 = (rest >> 1) * 64;
  const int tid = threadIdx.x;
  const int w = tid >> 6, l = tid & 63, lm = l & 15, quad = l >> 4;

  const short* qb = Q + ((size_t)b * 1024 + i0 + w * 16 + lm) * 512;
  bf8 aq[16];
#pragma unroll
  for (int kc = 0; kc < 16; ++kc) aq[kc] = *(const bf8*)&qb[kc * 32 + quad * 8];

  f32x4 oacc[16];
#pragma unroll
  for (int df = 0; df < 16; ++df) oacc[df] = (f32x4){0.f, 0.f, 0.f, 0.f};
  float lsum[4] = {0.f, 0.f, 0.f, 0.f};

  const short* kbase = Kb + (size_t)b * 524288;
  const short* vbase = VT + (size_t)b * 524288 + (size_t)dh * 262144;

  const int krow = tid & 31, kc0 = (tid >> 5) * 64;

  for (int j0 = 0; j0 < 1024; j0 += 32) {
    __syncthreads();
    {
      const short* src = kbase + (size_t)(j0 + krow) * 512 + kc0;
      short* dst = &KL[krow * 520 + kc0];
#pragma unroll
      for (int i = 0; i < 8; ++i) *(bf8*)&dst[i * 8] = *(const bf8*)&src[i * 8];
    }
    {
      const short* src = vbase + (size_t)tid * 1024 + j0;
      short* dst = &VL[tid * 40];
#pragma unroll
      for (int i = 0; i < 4; ++i) *(bf8*)&dst[i * 8] = *(const bf8*)&src[i * 8];
    }
    __syncthreads();

    f32x4 sacc[2];
    sacc[0] = (f32x4){0.f, 0.f, 0.f, 0.f};
    sacc[1] = (f32x4){0.f, 0.f, 0.f, 0.f};
#pragma unroll
    for (int kc = 0; kc < 16; ++kc) {
#pragma unroll
      for (int jf = 0; jf < 2; ++jf) {
        bf8 bk = *(const bf8*)&KL[(jf * 16 + lm) * 520 + kc * 32 + quad * 8];
        sacc[jf] = __builtin_amdgcn_mfma_f32_16x16x32_bf16(aq[kc], bk, sacc[jf], 0, 0, 0);
      }
    }
#pragma unroll
    for (int jf = 0; jf < 2; ++jf)
#pragma unroll
      for (int r = 0; r < 4; ++r) sacc[jf][r] = __expf(sacc[jf][r] * scale);
#pragma unroll
    for (int r = 0; r < 4; ++r) {
      float ts = sacc[0][r] + sacc[1][r];
      ts += __shfl_xor(ts, 1);
      ts += __shfl_xor(ts, 2);
      ts += __shfl_xor(ts, 4);
      ts += __shfl_xor(ts, 8);
      lsum[r] += ts;
      int row = quad * 4 + r;
      PL[w * 640 + row * 40 + lm] = f2b(sacc[0][r]);
      PL[w * 640 + row * 40 + 16 + lm] = f2b(sacc[1][r]);
    }
    bf8 ap = *(const bf8*)&PL[w * 640 + lm * 40 + quad * 8];
#pragma unroll
    for (int df = 0; df < 16; ++df) {
      bf8 bv = *(const bf8*)&VL[(df * 16 + lm) * 40 + quad * 8];
      oacc[df] = __builtin_amdgcn_mfma_f32_16x16x32_bf16(ap, bv, oacc[df], 0, 0, 0);
    }
  }
  float inv[4];
#pragma unroll
  for (int r = 0; r < 4; ++r) inv[r] = 1.f / lsum[r];
  short* ob = O + ((size_t)b * 1024 + i0 + w * 16 + quad * 4) * 512 + dh * 256;
#pragma unroll
  for (int df = 0; df < 16; ++df)
#pragma unroll
    for (int r = 0; r < 4; ++r)
      ob[(size_t)r * 512 + df * 16 + lm] = f2b(oacc[df][r] * inv[r]);
}

// ---------------------------------------------------------------------------
// Fused cross-attention via MFMA (unchanged).
__global__ __launch_bounds__(256) void cross_attn_mfma(const short* __restrict__ q2,
                                                       const short* __restrict__ k2,
                                                       const short* __restrict__ v2,
                                                       short* __restrict__ o2) {
  __shared__ short Pl[64 * 104];
  __shared__ short VTl[64 * 104];
  const int b = blockIdx.z, h = blockIdx.y, i0 = blockIdx.x * 64;
  const int tid = threadIdx.x;
  const int w = tid >> 6, l = tid & 63, lm = l & 15, quad = l >> 4;

  for (int idx = tid; idx < 64 * 104 / 4; idx += 256)
    *(bf4*)&VTl[idx * 4] = (bf4){0, 0, 0, 0};
  __syncthreads();
  for (int idx = tid; idx < 77 * 64; idx += 256) {
    int j = idx >> 6, d = idx & 63;
    VTl[d * 104 + j] = v2[(size_t)b * 39424 + j * 512 + h * 64 + d];
  }

  const short* qb = q2 + ((size_t)b * 1024 + i0 + w * 16 + lm) * 512 + h * 64;
  bf8 aq0 = *(const bf8*)&qb[quad * 8];
  bf8 aq1 = *(const bf8*)&qb[32 + quad * 8];
  const short* kb = k2 + (size_t)b * 39424 + h * 64;
  f32x4 sacc[5];
#pragma unroll
  for (int jt = 0; jt < 5; ++jt) sacc[jt] = (f32x4){0.f, 0.f, 0.f, 0.f};
#pragma unroll
  for (int jt = 0; jt < 5; ++jt) {
    int j = jt * 16 + lm;
    bf8 b0 = {0, 0, 0, 0, 0, 0, 0, 0}, b1 = {0, 0, 0, 0, 0, 0, 0, 0};
    if (j < 77) {
      b0 = *(const bf8*)&kb[j * 512 + quad * 8];
      b1 = *(const bf8*)&kb[j * 512 + 32 + quad * 8];
    }
    sacc[jt] = __builtin_amdgcn_mfma_f32_16x16x32_bf16(aq0, b0, sacc[jt], 0, 0, 0);
    sacc[jt] = __builtin_amdgcn_mfma_f32_16x16x32_bf16(aq1, b1, sacc[jt], 0, 0, 0);
  }
#pragma unroll
  for (int jt = 0; jt < 5; ++jt) {
    bool valid = (jt * 16 + lm) < 77;
#pragma unroll
    for (int r = 0; r < 4; ++r)
      sacc[jt][r] = valid ? sacc[jt][r] * 0.125f : -1e30f;
  }
#pragma unroll
  for (int r = 0; r < 4; ++r) {
    float mx = sacc[0][r];
#pragma unroll
    for (int jt = 1; jt < 5; ++jt) mx = fmaxf(mx, sacc[jt][r]);
    mx = fmaxf(mx, __shfl_xor(mx, 1));
    mx = fmaxf(mx, __shfl_xor(mx, 2));
    mx = fmaxf(mx, __shfl_xor(mx, 4));
    mx = fmaxf(mx, __shfl_xor(mx, 8));
    float s = 0.f;
    float e[5];
#pragma unroll
    for (int jt = 0; jt < 5; ++jt) { e[jt] = __expf(sacc[jt][r] - mx); s += e[jt]; }
    s += __shfl_xor(s, 1);
    s += __shfl_xor(s, 2);
    s += __shfl_xor(s, 4);
    s += __shfl_xor(s, 8);
    float iv = 1.f / s;
    int row = w * 16 + quad * 4 + r;
#pragma unroll
    for (int jt = 0; jt < 5; ++jt) Pl[row * 104 + jt * 16 + lm] = f2b(e[jt] * iv);
  }
#pragma unroll
  for (int r = 0; r < 4; ++r) Pl[(w * 16 + quad * 4 + r) * 104 + 80 + lm] = 0;
  __syncthreads();

  f32x4 oacc[4];
#pragma unroll
  for (int dt = 0; dt < 4; ++dt) oacc[dt] = (f32x4){0.f, 0.f, 0.f, 0.f};
#pragma unroll
  for (int kc = 0; kc < 3; ++kc) {
    bf8 ap = *(const bf8*)&Pl[(w * 16 + lm) * 104 + kc * 32 + quad * 8];
#pragma unroll
    for (int dt = 0; dt < 4; ++dt) {
      bf8 bv = *(const bf8*)&VTl[(dt * 16 + lm) * 104 + kc * 32 + quad * 8];
      oacc[dt] = __builtin_amdgcn_mfma_f32_16x16x32_bf16(ap, bv, oacc[dt], 0, 0, 0);
    }
  }
  short* ob = o2 + ((size_t)b * 1024 + i0 + w * 16 + quad * 4) * 512 + h * 64;
#pragma unroll
  for (int dt = 0; dt < 4; ++dt)
#pragma unroll
    for (int r = 0; r < 4; ++r)
      ob[(size_t)r * 512 + dt * 16 + lm] = f2b(oacc[dt][r]);
}

// ---------------------------------------------------------------------------
extern "C" void kernel_launch(void* const* d_in, const int* in_sizes, int n_in,
                              void* d_out, int out_size, void* d_ws, size_t ws_size,
                              hipStream_t stream) {
  const void* x       = d_in[0];
  const void* ctx     = d_in[1];
  const void* gn1_g   = d_in[2];
  const void* gn1_b   = d_in[3];
  const void* w_in    = d_in[4];
  const void* b_in    = d_in[5];
  const void* sa_wk   = d_in[6];
  const void* sa_wq   = d_in[7];
  const void* sa_wv   = d_in[8];
  const void* sa_wp   = d_in[9];
  const void* sa_gn_g = d_in[10];
  const void* sa_gn_b = d_in[11];
  const void* ca_wq   = d_in[12];
  const void* ca_wk   = d_in[13];
  const void* ca_wv   = d_in[14];
  const void* ca_wo   = d_in[15];
  const void* ca_bo   = d_in[16];
  const void* w_out   = d_in[17];
  const void* b_out   = d_in[18];

  const int B = 16;
  int NB = 16;
  while (NB > 1 && 131072ull + (size_t)NB * 5767168ull > ws_size) NB >>= 1;

  char* base = reinterpret_cast<char*>(d_ws);
  int* flagp = reinterpret_cast<int*>(base);
  float* smf = reinterpret_cast<float*>(base + 1024);
  float* stats1 = smf;
  float* stats2 = smf + 1024;
  float* s2 = smf + 10240;
  float* t2 = smf + 18432;
  char* big = base + 131072;
  const size_t MB = 1048576;
  short* U0 = (short*)(big + 0 * (size_t)NB * MB);
  short* U1 = (short*)(big + 1 * (size_t)NB * MB);
  short* U2 = (short*)(big + 2 * (size_t)NB * MB);
  short* U3 = (short*)(big + 3 * (size_t)NB * MB);
  short* U4 = (short*)(big + 4 * (size_t)NB * MB);
  char* Sreg = big + 5 * (size_t)NB * MB;
  short* xT = (short*)Sreg;
  short* k2 = (short*)Sreg;
  short* v2 = (short*)(Sreg + (size_t)NB * 78848);

  probe_dtype<<<1, 256, 0, stream>>>((const unsigned short*)x, flagp);

  const float qk_scale = 0.044194173824159216f;
  const int NOSPLIT = 1 << 30;

  for (int b0 = 0; b0 < B; b0 += NB) {
    size_t xoff = (size_t)b0 * 262144;
    size_t coff = (size_t)b0 * 59136;

    gn_stats_ext<<<NB * 32, 256, 0, stream>>>(x, xoff, flagp, stats1, 8, 256, 1024, 32);
    transpose_affine<<<dim3(16, NB), 256, 0, stream>>>(x, xoff, flagp, stats1, gn1_g, gn1_b, xT);
    mm<1, 0, 0, 0, 1, 0><<<dim3(4, 8, NB), 256, 0, stream>>>(
        w_in, 0, 256, 0, xT, 0, 256, 262144, U0, 0, 512, 524288,
        nullptr, 0, 0, 0.f, nullptr, b_in, flagp, 1.f, 1024, 256,
        w_in, U0, NOSPLIT);

    gn_stats2<<<NB * 32, 256, 0, stream>>>(U0, stats2);
    make_affine<<<(NB * 512 + 255) / 256, 256, 0, stream>>>(stats2, sa_gn_g, sa_gn_b, flagp, s2, t2, 512, 16, NB * 512);
    affine_apply<<<NB * 256, 256, 0, stream>>>(U0, s2, t2, U1);

    // q + k merged (independent, share B operand U1): y<8 -> q(U2), y>=8 -> k(U3)
    mm<1, 0, 0, 0, 0, 0><<<dim3(4, 16, NB), 256, 0, stream>>>(
        sa_wq, 0, 512, 0, U1, 0, 512, 524288, U2, 0, 512, 524288,
        nullptr, 0, 0, 0.f, nullptr, nullptr, flagp, 1.f, 1024, 512,
        sa_wk, U3, 8);
    mm<0, 1, 0, 0, 0, 0><<<dim3(8, 4, NB), 256, 0, stream>>>(
        U1, 0, 512, 524288, sa_wv, 0, 512, 0, U4, 0, 1024, 524288,
        nullptr, 0, 0, 0.f, nullptr, nullptr, flagp, 1.f, 512, 512,
        U1, U4, NOSPLIT);

    flash_attn<<<dim3(32 * NB), 256, 0, stream>>>(U2, U3, U4, U1, qk_scale, NB - 1);

    mm<1, 0, 0, 0, 0, 1><<<dim3(4, 8, NB), 256, 0, stream>>>(
        sa_wp, 0, 512, 0, U1, 0, 512, 524288, U3, 0, 512, 524288,
        U0, 0, 524288, 2.f, nullptr, nullptr, flagp, 1.f, 1024, 512,
        sa_wp, U3, NOSPLIT);

    mm<1, 0, 0, 0, 0, 0><<<dim3(4, 8, NB), 256, 0, stream>>>(
        ca_wq, 0, 512, 0, U3, 0, 512, 524288, U2, 0, 512, 524288,
        nullptr, 0, 0, 0.f, nullptr, nullptr, flagp, 1.f, 1024, 512,
        ca_wq, U2, NOSPLIT);
    // ca_wk + ca_wv merged (independent, share B operand ctx): y=0 -> k2, y=1 -> v2
    mm<1, 1, 0, 0, 0, 0><<<dim3(4, 2, NB), 256, 0, stream>>>(
        ca_wk, 0, 768, 0, ctx, coff, 768, 59136, k2, 0, 512, 39424,
        nullptr, 0, 0, 0.f, nullptr, nullptr, flagp, 1.f, 77, 768,
        ca_wv, v2, 1);
    cross_attn_mfma<<<dim3(16, 8, NB), 256, 0, stream>>>(U2, k2, v2, U4);

    mm<1, 0, 0, 0, 1, 1><<<dim3(4, 8, NB), 256, 0, stream>>>(
        ca_wo, 0, 512, 0, U4, 0, 512, 524288, U0, 0, 512, 524288,
        U3, 0, 524288, 1.f, nullptr, ca_bo, flagp, 1.f, 1024, 512,
        ca_wo, U0, NOSPLIT);

    mm<0, 1, 2, 1, 0, 2><<<dim3(8, 2, NB), 256, 0, stream>>>(
        U0, 0, 512, 524288, w_out, 0, 512, 0, d_out, xoff, 1024, 262144,
        x, xoff, 262144, 1.f, b_out, nullptr, flagp, 1.f, 256, 512,
        U0, d_out, NOSPLIT);
  }

  (void)in_sizes; (void)n_in; (void)out_size;
}